// Round 13
// baseline (131.302 us; speedup 1.0000x reference)
//
#include <hip/hip_runtime.h>
#include <math.h>

#define NNODE 32768     // B*T*N
#define NEDGE 524288    // NNODE * DEG
#define DD 64           // feature dim D

typedef float  f32x4 __attribute__((ext_vector_type(4)));
typedef short  s16x8 __attribute__((ext_vector_type(8)));

__device__ __forceinline__ float silu_f(float x) {
    return x * __builtin_amdgcn_rcpf(1.0f + __expf(-x));
}
__device__ __forceinline__ unsigned cvt_pk_bf16(float a, float b) {
    unsigned r;
    asm("v_cvt_pk_bf16_f32 %0, %1, %2" : "=v"(r) : "v"(a), "v"(b));
    return r;   // [15:0]=bf16(a), [31:16]=bf16(b), RNE
}
__device__ __forceinline__ unsigned short bf16r(float f) {
    unsigned u = __float_as_uint(f);
    unsigned r = (u + 0x7FFFu + ((u >> 16) & 1u)) >> 16;
    return (unsigned short)r;
}
__device__ __forceinline__ float bf16f(unsigned short u) {
    return __uint_as_float(((unsigned)u) << 16);
}
// wave-private LDS ordering: wait LDS ops, pin scheduling (no s_barrier!)
__device__ __forceinline__ void wsync() {
    asm volatile("s_waitcnt lgkmcnt(0)" ::: "memory");
    __builtin_amdgcn_sched_barrier(0);
}

// fused: pos prep (blocks 0..127) + dst histogram (non-returning atomics) + base/wfrag (block 2048)
__global__ __launch_bounds__(256) void k_prep_hist_base(
    const float* __restrict__ x, const float* __restrict__ x1,
    const float* __restrict__ vm, float* __restrict__ pos,
    const int* __restrict__ ei, int* __restrict__ cnt,
    const float* __restrict__ Wsp, const float* __restrict__ Wt,
    const float* __restrict__ Wm, const float* __restrict__ Wu,
    const float* __restrict__ We, const float* __restrict__ tarr,
    float* __restrict__ base_ws, unsigned short* __restrict__ wfrag)
{
    int tid = threadIdx.x, b = blockIdx.x;
    if (b >= 2048) {
        if (tid < 64) {
            float t0 = tarr[0], t1 = tarr[1];
            float aA = 0.0f, aB = 0.0f;
            for (int k = 0; k < DD; ++k) {
                float w = Wm[k*DD + tid] + Wm[(DD+k)*DD + tid];
                aA = fmaf(Wsp[k] + t0*Wt[k], w, aA);
                aB = fmaf(Wsp[k] + t1*Wt[k], w, aB);
            }
            base_ws[tid]      = aA;
            base_ws[DD + tid] = aB;
        }
        // wfrag[0:4096) = W_msg[128:192] B-frags; [4096:8192) = W_upd B-frags;
        // [8192:10240) = W_edge B-frags (K=4 padded to 32)
        for (int idx = tid; idx < 10240; idx += 256) {
            unsigned short v;
            if (idx < 8192) {
                int sel = idx >> 12, id2 = idx & 4095;
                int j  = id2 & 7;
                int ln = (id2 >> 3) & 63;
                int ts = id2 >> 9;
                int t2 = ts >> 1, s = ts & 1;
                int k   = s*32 + (ln >> 4)*8 + j;
                int col = t2*16 + (ln & 15);
                v = bf16r(sel ? Wu[k*DD + col] : Wm[(128 + k)*DD + col]);
            } else {
                int id3 = idx - 8192;
                int j = id3 & 7, ln = (id3 >> 3) & 63, t2 = id3 >> 9;
                v = (ln < 16 && j < 4) ? bf16r(We[j*DD + t2*16 + (ln & 15)])
                                       : (unsigned short)0;
            }
            wfrag[idx] = v;
        }
        return;
    }
    if (b < 128) {
        int i = b*256 + tid;
        float m = vm[i];
        #pragma unroll
        for (int c = 0; c < 3; ++c)
            pos[i*3+c] = x[i*3+c]*m + x1[i*3+c]*(1.0f-m);
    }
    int e = b*256 + tid;
    atomicAdd(&cnt[ei[NEDGE + e]], 1);
}

// per-structure exclusive scan -> rowptr + cursor copy (each structure = 65536 edges)
__global__ __launch_bounds__(1024) void k_scan(
    const int* __restrict__ cnt, int* __restrict__ rowptr, int* __restrict__ cursor)
{
    __shared__ int buf[2][1024];
    const int g = blockIdx.x;          // 8 blocks
    const int tid = threadIdx.x;
    int4 L = ((const int4*)cnt)[g*1024 + tid];
    int s = L.x + L.y + L.z + L.w;
    buf[0][tid] = s;
    __syncthreads();
    int pp = 0;
    for (int off = 1; off < 1024; off <<= 1) {
        int v = buf[pp][tid];
        if (tid >= off) v += buf[pp][tid - off];
        buf[pp^1][tid] = v;
        __syncthreads();
        pp ^= 1;
    }
    int ex = (tid ? buf[pp][tid-1] : 0) + g*65536;
    int4 o;
    o.x = ex; ex += L.x;
    o.y = ex; ex += L.y;
    o.z = ex; ex += L.z;
    o.w = ex; ex += L.w;
    ((int4*)rowptr)[g*1024 + tid] = o;
    ((int4*)cursor)[g*1024 + tid] = o;
    if (g == 7 && tid == 1023) rowptr[32768] = NEDGE;
}

// geometry + counting-sort scatter via cursor: srec[slot] = {ev,len}, sdst[slot] = dst
__global__ __launch_bounds__(256) void k_sortgeo(
    const int* __restrict__ ei, const int* __restrict__ tj,
    const float* __restrict__ pos, const float* __restrict__ cell,
    int* __restrict__ cursor,
    float4* __restrict__ srec, int* __restrict__ sdst)
{
    int e = blockIdx.x * 256 + threadIdx.x;         // 2048 blocks
    int g = e >> 16;
    int src = ei[e];
    int dst = ei[NEDGE + e];
    const float* cl = cell + g*9;
    float c00=cl[0],c01=cl[1],c02=cl[2],c10=cl[3],c11=cl[4],c12=cl[5],c20=cl[6],c21=cl[7],c22=cl[8];
    float tj0 = (float)tj[e*3+0], tj1 = (float)tj[e*3+1], tj2 = (float)tj[e*3+2];
    float ev0 = pos[dst*3+0] - pos[src*3+0] + tj0*c00 + tj1*c10 + tj2*c20;
    float ev1 = pos[dst*3+1] - pos[src*3+1] + tj0*c01 + tj1*c11 + tj2*c21;
    float ev2 = pos[dst*3+2] - pos[src*3+2] + tj0*c02 + tj1*c12 + tj2*c22;
    float len = sqrtf(ev0*ev0 + ev1*ev1 + ev2*ev2 + 1e-12f);
    int slot = atomicAdd(&cursor[dst], 1);
    srec[slot] = (float4){ev0, ev1, ev2, len};
    sdst[slot] = dst;
}

// One wave (64-thread block) per 4-node group (8192 blocks). Batched window
// pipeline: 5 lgkmcnt drain-points per 64-edge window (was 16). CSR slice,
// coalesced sorted reads + register prefetch, ea via MFMA, per-node agg/v in
// LDS (exclusive, no atomics), fused gate+readout.
__global__ __launch_bounds__(64) void k_edge_all(
    const float4* __restrict__ srec, const int* __restrict__ sdst,
    const int* __restrict__ rowptr,
    const unsigned short* __restrict__ wfrag,
    const float* __restrict__ base_ws,
    const float* __restrict__ Wsp, const float* __restrict__ Wt,
    const float* __restrict__ wdec, const float* __restrict__ tarr,
    const float* __restrict__ vm, float* __restrict__ out)
{
    const int lane = threadIdx.x;
    const int lo16 = lane & 15;
    const int hi   = lane >> 4;
    const int grp  = (blockIdx.x & 7) * 1024 + (blockIdx.x >> 3);  // XCD-local slice
    const int n0   = grp * 4;

    // LDS 13824 B:
    // @0     edge4 f4[64] (1024) | @1024 dstl i32[64] (256)
    // @1280  ea u16[4][16][72] (9216) ALIAS msgb u16[4][64][20] (10240) -> union 10240
    // @11520 agg_l u16[4][72] (576; node-phase A-reads overrun into v_l+pad, guarded)
    // @12096 v_l u16[12][64] (1536) | pad to 13824 covers A-read overrun
    __shared__ __align__(16) char my[13824];
    float4*         edge4 = (float4*)my;
    int*            dstl  = (int*)(my + 1024);
    unsigned short* ealds = (unsigned short*)(my + 1280);
    unsigned short* msgb  = (unsigned short*)(my + 1280);
    unsigned short* agg_l = (unsigned short*)(my + 11520);
    unsigned short* v_l   = (unsigned short*)(my + 12096);

    // zero agg_l + v_l (2112 B = 528 dwords)
    {
        int* zp = (int*)(my + 11520);
        #pragma unroll
        for (int j = 0; j < 9; ++j) {
            int o = j*64 + lane;
            if (o < 528) zp[o] = 0;
        }
    }

    // hot uniforms (node-phase constants loaded later)
    s16x8 bfr[4][2], wfe[4];
    #pragma unroll
    for (int t2 = 0; t2 < 4; ++t2) {
        #pragma unroll
        for (int s = 0; s < 2; ++s)
            bfr[t2][s] = *(const s16x8*)(wfrag + ((t2*2+s)*64 + lane)*8);
        wfe[t2] = *(const s16x8*)(wfrag + 8192 + (t2*64 + lane)*8);
    }
    const bool  sb  = (n0 >> 14) != 0;         // batch
    float bv4[4];
    #pragma unroll
    for (int t2 = 0; t2 < 4; ++t2)
        bv4[t2] = base_ws[(sb ? DD : 0) + t2*16 + lo16];

    const int estart = rowptr[n0];
    const int eend   = rowptr[n0 + 4];

    int   curn = -1;
    float s0 = 0.f, sva = 0.f, svb = 0.f, svc = 0.f;

    int ebase = estart;
    int cnt64 = eend - ebase; if (cnt64 > 64) cnt64 = 64;
    float4 r_rec = {0.f,0.f,0.f,0.f};
    int    r_dst = 0;
    if (ebase < eend) {
        int ii = ebase + (lane < cnt64 ? lane : cnt64 - 1);
        r_rec = srec[ii];
        r_dst = sdst[ii];
    }

    while (ebase < eend) {
        edge4[lane] = r_rec;
        dstl[lane]  = r_dst;
        wsync();                                // window visible (wave-private)

        // prefetch next window (stays in flight under compute)
        int nb = ebase + 64;
        if (nb < eend) {
            int c2 = eend - nb; if (c2 > 64) c2 = 64;
            int jj = nb + (lane < c2 ? lane : c2 - 1);
            r_rec = srec[jj];
            r_dst = sdst[jj];
        }

        const int nsub = (cnt64 + 15) >> 4;

        // ---- stage 1: ea via MFMA for ALL subtiles ----
        #pragma unroll
        for (int i = 0; i < 4; ++i) if (i < nsub) {
            float4 q = edge4[i*16 + lo16];      // 16 rows, broadcast across hi
            unsigned pa0 = cvt_pk_bf16(q.x, q.y);
            unsigned pa1 = cvt_pk_bf16(q.z, q.w);
            uint4 av = (hi == 0) ? (uint4){pa0, pa1, 0u, 0u}
                                 : (uint4){0u, 0u, 0u, 0u};
            s16x8 aea = *reinterpret_cast<s16x8*>(&av);
            #pragma unroll
            for (int t2 = 0; t2 < 4; ++t2) {
                f32x4 pre = {0.f, 0.f, 0.f, 0.f};
                pre = __builtin_amdgcn_mfma_f32_16x16x32_bf16(aea, wfe[t2], pre, 0, 0, 0);
                #pragma unroll
                for (int r = 0; r < 4; ++r)
                    ealds[i*1152 + (hi*4+r)*72 + t2*16 + lo16] =
                        (unsigned short)cvt_pk_bf16(silu_f(pre[r]), 0.f);
            }
        }
        wsync();                                // all ea tiles visible

        // ---- stage 2: A-frags for ALL subtiles (static-indexed arrays) ----
        s16x8 a0[4], a1[4];
        #pragma unroll
        for (int i = 0; i < 4; ++i) if (i < nsub) {
            const unsigned short* arow = ealds + i*1152 + lo16*72 + hi*8;
            a0[i] = *(const s16x8*)(arow);
            a1[i] = *(const s16x8*)(arow + 32);
        }
        wsync();                                // frags in regs; region reusable (msgb alias)

        // ---- stage 3: msg MFMAs for ALL subtiles ----
        #pragma unroll
        for (int i = 0; i < 4; ++i) if (i < nsub) {
            #pragma unroll
            for (int t2 = 0; t2 < 4; ++t2) {
                const float bvt = bv4[t2];
                f32x4 acc = {bvt, bvt, bvt, bvt};   // base bias folded into C
                acc = __builtin_amdgcn_mfma_f32_16x16x32_bf16(a0[i], bfr[t2][0], acc, 0, 0, 0);
                acc = __builtin_amdgcn_mfma_f32_16x16x32_bf16(a1[i], bfr[t2][1], acc, 0, 0, 0);
                unsigned u0 = cvt_pk_bf16(silu_f(acc[0]), silu_f(acc[1]));
                unsigned u1 = cvt_pk_bf16(silu_f(acc[2]), silu_f(acc[3]));
                *reinterpret_cast<uint2*>(msgb + i*1280 + (t2*16+lo16)*20 + hi*4) = (uint2){u0, u1};
            }
        }
        wsync();                                // msg tiles visible

        // ---- stage 4: segmented reduce across the whole window ----
        #pragma unroll
        for (int i = 0; i < 4; ++i) if (i < nsub) {
            int rows = cnt64 - i*16; if (rows > 16) rows = 16;
            #pragma unroll
            for (int rb = 0; rb < 4; ++rb) if (rb*4 < rows) {
                uint2 mm = *reinterpret_cast<const uint2*>(msgb + i*1280 + lane*20 + rb*4);
                float m0 = __uint_as_float(mm.x << 16);
                float m1 = __uint_as_float(mm.x & 0xffff0000u);
                float m2 = __uint_as_float(mm.y << 16);
                float m3 = __uint_as_float(mm.y & 0xffff0000u);
                #pragma unroll
                for (int rr = 0; rr < 4; ++rr) {
                    int rl = rb*4 + rr;
                    if (rl < rows) {
                        int nd = dstl[i*16 + rl];   // uniform broadcast
                        if (nd != curn) {           // wave-uniform branch
                            if (curn >= 0) {
                                int nl = curn - n0;
                                agg_l[nl*72 + lane]     = (unsigned short)cvt_pk_bf16(s0, s0);
                                v_l[(nl*3+0)*64 + lane] = (unsigned short)cvt_pk_bf16(sva, sva);
                                v_l[(nl*3+1)*64 + lane] = (unsigned short)cvt_pk_bf16(svb, svb);
                                v_l[(nl*3+2)*64 + lane] = (unsigned short)cvt_pk_bf16(svc, svc);
                            }
                            s0 = sva = svb = svc = 0.f;
                            curn = nd;
                        }
                        float4 q2 = edge4[i*16 + rl];
                        float m = rr==0 ? m0 : rr==1 ? m1 : rr==2 ? m2 : m3;
                        s0 += m;
                        sva = fmaf(q2.x, m, sva);
                        svb = fmaf(q2.y, m, svb);
                        svc = fmaf(q2.z, m, svc);
                    }
                }
            }
        }
        wsync();                                // seg reads done before next window

        ebase = nb;
        cnt64 = eend - ebase; if (cnt64 > 64) cnt64 = 64;
    }
    if (curn >= 0) {
        int nl = curn - n0;
        agg_l[nl*72 + lane]     = (unsigned short)cvt_pk_bf16(s0, s0);
        v_l[(nl*3+0)*64 + lane] = (unsigned short)cvt_pk_bf16(sva, sva);
        v_l[(nl*3+1)*64 + lane] = (unsigned short)cvt_pk_bf16(svb, svb);
        v_l[(nl*3+2)*64 + lane] = (unsigned short)cvt_pk_bf16(svc, svc);
    }
    wsync();

    // ---- node phase: gate = silu(h + silu(agg@Wu)) * wdec; out = vm * (v . gate) ----
    s16x8 wub[4][2];
    #pragma unroll
    for (int t2 = 0; t2 < 4; ++t2)
        #pragma unroll
        for (int s = 0; s < 2; ++s)
            wub[t2][s] = *(const s16x8*)(wfrag + 4096 + ((t2*2+s)*64 + lane)*8);
    const float tb = sb ? tarr[1] : tarr[0];
    float hb4[4], wd4[4];
    #pragma unroll
    for (int t2 = 0; t2 < 4; ++t2) {
        hb4[t2] = Wsp[t2*16+lo16] + tb * Wt[t2*16+lo16];
        wd4[t2] = wdec[t2*16+lo16];
    }
    // A-tile: rows 0..3 real agg, rows 4..15 garbage (guarded below)
    s16x8 ga0 = *(const s16x8*)(agg_l + lo16*72 + hi*8);
    s16x8 ga1 = *(const s16x8*)(agg_l + lo16*72 + hi*8 + 32);
    float p[4][3] = {{0.f,0.f,0.f},{0.f,0.f,0.f},{0.f,0.f,0.f},{0.f,0.f,0.f}};
    #pragma unroll
    for (int t2 = 0; t2 < 4; ++t2) {
        f32x4 accg = {0.f, 0.f, 0.f, 0.f};
        accg = __builtin_amdgcn_mfma_f32_16x16x32_bf16(ga0, wub[t2][0], accg, 0, 0, 0);
        accg = __builtin_amdgcn_mfma_f32_16x16x32_bf16(ga1, wub[t2][1], accg, 0, 0, 0);
        #pragma unroll
        for (int r = 0; r < 4; ++r) {
            int node = hi*4 + r;
            float hn   = hb4[t2] + silu_f(accg[r]);
            float gate = silu_f(hn) * wd4[t2];
            if (node < 4) {
                #pragma unroll
                for (int c = 0; c < 3; ++c) {
                    float vv = bf16f(v_l[(node*3+c)*64 + t2*16 + lo16]);
                    p[r][c] = fmaf(gate, vv, p[r][c]);
                }
            }
        }
    }
    #pragma unroll
    for (int st = 1; st < 16; st <<= 1)
        #pragma unroll
        for (int r = 0; r < 4; ++r)
            #pragma unroll
            for (int c = 0; c < 3; ++c)
                p[r][c] += __shfl_xor(p[r][c], st, 64);

    if (lo16 < 12 && hi == 0) {
        int rr = lo16 / 3, c = lo16 - rr*3;
        float val = rr==0 ? (c==0 ? p[0][0] : c==1 ? p[0][1] : p[0][2])
                  : rr==1 ? (c==0 ? p[1][0] : c==1 ? p[1][1] : p[1][2])
                  : rr==2 ? (c==0 ? p[2][0] : c==1 ? p[2][1] : p[2][2])
                  :         (c==0 ? p[3][0] : c==1 ? p[3][1] : p[3][2]);
        out[(n0 + rr)*3 + c] = val * vm[n0 + rr];
    }
}

extern "C" void kernel_launch(void* const* d_in, const int* in_sizes, int n_in,
                              void* d_out, int out_size, void* d_ws, size_t ws_size,
                              hipStream_t stream) {
    const float* x    = (const float*)d_in[0];
    const float* t    = (const float*)d_in[1];
    const float* cell = (const float*)d_in[2];
    const float* x1   = (const float*)d_in[3];
    const float* vm   = (const float*)d_in[4];
    const float* Wsp  = (const float*)d_in[5];
    const float* Wt   = (const float*)d_in[6];
    const float* We   = (const float*)d_in[7];
    const float* Wm   = (const float*)d_in[8];
    const float* Wu   = (const float*)d_in[9];
    const float* wdec = (const float*)d_in[10];
    const int*   ei   = (const int*)d_in[11];
    const int*   tj   = (const int*)d_in[12];
    float* out = (float*)d_out;

    // ws layout (float units):
    float*  ws      = (float*)d_ws;
    float4* srec    = (float4*)ws;                   // [524288] f4
    int*    sdst    = (int*)(ws + 2097152);          // [524288]
    float*  pos     = ws + 2621440;                  // [98304]
    int*    rowptr  = (int*)(pos + 98304);           // [32784 pad]
    int*    cursor  = rowptr + 32784;                // [32784 pad]
    int*    cnt     = cursor + 32784;                // [32768]
    float*  base_ws = (float*)(cnt + 32768);         // [128]
    unsigned short* wfrag = (unsigned short*)(base_ws + 128);  // [10240]

    hipMemsetAsync(cnt, 0, 32768*sizeof(int), stream);
    k_prep_hist_base<<<2049, 256, 0, stream>>>(x, x1, vm, pos, ei, cnt,
                                               Wsp, Wt, Wm, Wu, We, t, base_ws, wfrag);
    k_scan<<<8, 1024, 0, stream>>>(cnt, rowptr, cursor);
    k_sortgeo<<<2048, 256, 0, stream>>>(ei, tj, pos, cell, cursor, srec, sdst);
    k_edge_all<<<8192, 64, 0, stream>>>(srec, sdst, rowptr, wfrag, base_ws,
                                        Wsp, Wt, wdec, t, vm, out);
}

// Round 14
// 109.187 us; speedup vs baseline: 1.2025x; 1.2025x over previous
//
#include <hip/hip_runtime.h>
#include <math.h>

#define NNODE 32768     // B*T*N
#define NEDGE 524288    // NNODE * DEG
#define DD 64           // feature dim D

typedef float  f32x4 __attribute__((ext_vector_type(4)));
typedef short  s16x8 __attribute__((ext_vector_type(8)));

__device__ __forceinline__ float silu_f(float x) {
    return x * __builtin_amdgcn_rcpf(1.0f + __expf(-x));
}
__device__ __forceinline__ unsigned cvt_pk_bf16(float a, float b) {
    unsigned r;
    asm("v_cvt_pk_bf16_f32 %0, %1, %2" : "=v"(r) : "v"(a), "v"(b));
    return r;   // [15:0]=bf16(a), [31:16]=bf16(b), RNE
}
__device__ __forceinline__ unsigned short bf16r(float f) {
    unsigned u = __float_as_uint(f);
    unsigned r = (u + 0x7FFFu + ((u >> 16) & 1u)) >> 16;
    return (unsigned short)r;
}
__device__ __forceinline__ float bf16f(unsigned short u) {
    return __uint_as_float(((unsigned)u) << 16);
}
// wave-private LDS ordering: wait LDS ops, pin scheduling (no s_barrier!)
__device__ __forceinline__ void wsync() {
    asm volatile("s_waitcnt lgkmcnt(0)" ::: "memory");
    __builtin_amdgcn_sched_barrier(0);
}

// fused: pos prep (blocks 0..127) + dst histogram/rank (blocks 0..2047) + base/wfrag (block 2048)
__global__ __launch_bounds__(256) void k_prep_hist_base(
    const float* __restrict__ x, const float* __restrict__ x1,
    const float* __restrict__ vm, float* __restrict__ pos,
    const int* __restrict__ ei, int* __restrict__ cnt, int* __restrict__ rank,
    const float* __restrict__ Wsp, const float* __restrict__ Wt,
    const float* __restrict__ Wm, const float* __restrict__ Wu,
    const float* __restrict__ We, const float* __restrict__ tarr,
    float* __restrict__ base_ws, unsigned short* __restrict__ wfrag)
{
    int tid = threadIdx.x, b = blockIdx.x;
    if (b >= 2048) {
        if (tid < 64) {
            float t0 = tarr[0], t1 = tarr[1];
            float aA = 0.0f, aB = 0.0f;
            for (int k = 0; k < DD; ++k) {
                float w = Wm[k*DD + tid] + Wm[(DD+k)*DD + tid];
                aA = fmaf(Wsp[k] + t0*Wt[k], w, aA);
                aB = fmaf(Wsp[k] + t1*Wt[k], w, aB);
            }
            base_ws[tid]      = aA;
            base_ws[DD + tid] = aB;
        }
        // wfrag[0:4096) = W_msg[128:192] B-frags; [4096:8192) = W_upd B-frags;
        // [8192:10240) = W_edge B-frags (K=4 padded to 32)
        for (int idx = tid; idx < 10240; idx += 256) {
            unsigned short v;
            if (idx < 8192) {
                int sel = idx >> 12, id2 = idx & 4095;
                int j  = id2 & 7;
                int ln = (id2 >> 3) & 63;
                int ts = id2 >> 9;
                int t2 = ts >> 1, s = ts & 1;
                int k   = s*32 + (ln >> 4)*8 + j;
                int col = t2*16 + (ln & 15);
                v = bf16r(sel ? Wu[k*DD + col] : Wm[(128 + k)*DD + col]);
            } else {
                int id3 = idx - 8192;
                int j = id3 & 7, ln = (id3 >> 3) & 63, t2 = id3 >> 9;
                v = (ln < 16 && j < 4) ? bf16r(We[j*DD + t2*16 + (ln & 15)])
                                       : (unsigned short)0;
            }
            wfrag[idx] = v;
        }
        return;
    }
    if (b < 128) {
        int i = b*256 + tid;
        float m = vm[i];
        #pragma unroll
        for (int c = 0; c < 3; ++c)
            pos[i*3+c] = x[i*3+c]*m + x1[i*3+c]*(1.0f-m);
    }
    int e = b*256 + tid;
    rank[e] = atomicAdd(&cnt[ei[NEDGE + e]], 1);
}

// per-structure exclusive scan (each structure has exactly 65536 edges)
__global__ __launch_bounds__(1024) void k_scan(
    const int* __restrict__ cnt, int* __restrict__ rowptr)
{
    __shared__ int buf[2][1024];
    const int g = blockIdx.x;          // 8 blocks
    const int tid = threadIdx.x;
    int4 L = ((const int4*)cnt)[g*1024 + tid];
    int s = L.x + L.y + L.z + L.w;
    buf[0][tid] = s;
    __syncthreads();
    int pp = 0;
    for (int off = 1; off < 1024; off <<= 1) {
        int v = buf[pp][tid];
        if (tid >= off) v += buf[pp][tid - off];
        buf[pp^1][tid] = v;
        __syncthreads();
        pp ^= 1;
    }
    int ex = (tid ? buf[pp][tid-1] : 0) + g*65536;
    int4 o;
    o.x = ex; ex += L.x;
    o.y = ex; ex += L.y;
    o.z = ex; ex += L.z;
    o.w = ex; ex += L.w;
    ((int4*)rowptr)[g*1024 + tid] = o;
    if (g == 7 && tid == 1023) rowptr[32768] = NEDGE;
}

// geometry + counting-sort scatter: srec[slot] = {ev,len}, sdst[slot] = dst
__global__ __launch_bounds__(256) void k_sortgeo(
    const int* __restrict__ ei, const int* __restrict__ tj,
    const float* __restrict__ pos, const float* __restrict__ cell,
    const int* __restrict__ rowptr, const int* __restrict__ rank,
    float4* __restrict__ srec, int* __restrict__ sdst)
{
    int e = blockIdx.x * 256 + threadIdx.x;         // 2048 blocks
    int g = e >> 16;
    int src = ei[e];
    int dst = ei[NEDGE + e];
    const float* cl = cell + g*9;
    float c00=cl[0],c01=cl[1],c02=cl[2],c10=cl[3],c11=cl[4],c12=cl[5],c20=cl[6],c21=cl[7],c22=cl[8];
    float tj0 = (float)tj[e*3+0], tj1 = (float)tj[e*3+1], tj2 = (float)tj[e*3+2];
    float ev0 = pos[dst*3+0] - pos[src*3+0] + tj0*c00 + tj1*c10 + tj2*c20;
    float ev1 = pos[dst*3+1] - pos[src*3+1] + tj0*c01 + tj1*c11 + tj2*c21;
    float ev2 = pos[dst*3+2] - pos[src*3+2] + tj0*c02 + tj1*c12 + tj2*c22;
    float len = sqrtf(ev0*ev0 + ev1*ev1 + ev2*ev2 + 1e-12f);
    int slot = rowptr[dst] + rank[e];
    srec[slot] = (float4){ev0, ev1, ev2, len};
    sdst[slot] = dst;
}

// 128-thread blocks = 2 INDEPENDENT wave-slices (no inter-wave coupling, no
// s_barrier). Each wave: one 4-node group, CSR slice, coalesced sorted reads +
// register prefetch, ea via MFMA, per-node agg/v in LDS, fused gate+readout.
// 2 waves/WG doubles waves-per-WG-slot (the binding residency limit).
__global__ __launch_bounds__(128) void k_edge_all(
    const float4* __restrict__ srec, const int* __restrict__ sdst,
    const int* __restrict__ rowptr,
    const unsigned short* __restrict__ wfrag,
    const float* __restrict__ base_ws,
    const float* __restrict__ Wsp, const float* __restrict__ Wt,
    const float* __restrict__ wdec, const float* __restrict__ tarr,
    const float* __restrict__ vm, float* __restrict__ out)
{
    const int lane = threadIdx.x & 63;
    const int wid  = threadIdx.x >> 6;
    const int lo16 = lane & 15;
    const int hi   = lane >> 4;
    const int grp  = (blockIdx.x & 7) * 1024 + (blockIdx.x >> 3) * 2 + wid;  // XCD slice
    const int n0   = grp * 4;

    // per-wave LDS slice 6144 B:
    // @0 edge4 f4[64] | @1024 dstl i32[64] | @1280 ea[16][72] u16 ALIAS msgb[64][20] u16
    // @3840 agg_l [4][72] u16 (A-read window extends to 6144; rows>=4 garbage, guarded)
    // @4416 v_l [12][64] u16
    __shared__ __align__(16) char smem[2][6144];
    char* my = smem[wid];
    float4*         edge4 = (float4*)my;
    int*            dstl  = (int*)(my + 1024);
    unsigned short* ealds = (unsigned short*)(my + 1280);
    unsigned short* msgb  = (unsigned short*)(my + 1280);
    unsigned short* agg_l = (unsigned short*)(my + 3840);
    unsigned short* v_l   = (unsigned short*)(my + 4416);

    // zero agg_l (4 rows) + v_l: 576+1536 B = 528 dwords
    {
        int* zp = (int*)(my + 3840);
        #pragma unroll
        for (int j = 0; j < 9; ++j) {
            int o = j*64 + lane;
            if (o < 528) zp[o] = 0;
        }
    }

    // hot uniforms (node-phase constants loaded later)
    s16x8 bfr[4][2], wfe[4];
    #pragma unroll
    for (int t2 = 0; t2 < 4; ++t2) {
        #pragma unroll
        for (int s = 0; s < 2; ++s)
            bfr[t2][s] = *(const s16x8*)(wfrag + ((t2*2+s)*64 + lane)*8);
        wfe[t2] = *(const s16x8*)(wfrag + 8192 + (t2*64 + lane)*8);
    }
    const bool  sb  = (n0 >> 14) != 0;         // batch
    float bv4[4];
    #pragma unroll
    for (int t2 = 0; t2 < 4; ++t2)
        bv4[t2] = base_ws[(sb ? DD : 0) + t2*16 + lo16];

    const int estart = rowptr[n0];
    const int eend   = rowptr[n0 + 4];

    int   curn = -1;
    float s0 = 0.f, sva = 0.f, svb = 0.f, svc = 0.f;

    int ebase = estart;
    int cnt64 = eend - ebase; if (cnt64 > 64) cnt64 = 64;
    float4 r_rec = {0.f,0.f,0.f,0.f};
    int    r_dst = 0;
    if (ebase < eend) {
        int ii = ebase + (lane < cnt64 ? lane : cnt64 - 1);
        r_rec = srec[ii];
        r_dst = sdst[ii];
    }

    while (ebase < eend) {
        edge4[lane] = r_rec;
        dstl[lane]  = r_dst;
        wsync();                                // window visible (wave-private)

        // prefetch next window (stays in flight under compute)
        int nb = ebase + 64;
        if (nb < eend) {
            int c2 = eend - nb; if (c2 > 64) c2 = 64;
            int jj = nb + (lane < c2 ? lane : c2 - 1);
            r_rec = srec[jj];
            r_dst = sdst[jj];
        }

        int nsub = (cnt64 + 15) >> 4;
        for (int i = 0; i < nsub; ++i) {
            // ---- ea stage via MFMA (K=4 in a 16x16x32) ----
            float4 q = edge4[i*16 + lo16];      // 16 rows, broadcast across hi
            unsigned pa0 = cvt_pk_bf16(q.x, q.y);
            unsigned pa1 = cvt_pk_bf16(q.z, q.w);
            uint4 av = (hi == 0) ? (uint4){pa0, pa1, 0u, 0u}
                                 : (uint4){0u, 0u, 0u, 0u};
            s16x8 aea = *reinterpret_cast<s16x8*>(&av);
            #pragma unroll
            for (int t2 = 0; t2 < 4; ++t2) {
                f32x4 pre = {0.f, 0.f, 0.f, 0.f};
                pre = __builtin_amdgcn_mfma_f32_16x16x32_bf16(aea, wfe[t2], pre, 0, 0, 0);
                #pragma unroll
                for (int r = 0; r < 4; ++r)
                    ealds[(hi*4+r)*72 + t2*16 + lo16] =
                        (unsigned short)cvt_pk_bf16(silu_f(pre[r]), 0.f);
            }
            wsync();                            // ea tile visible

            const unsigned short* arow = ealds + lo16*72 + hi*8;
            s16x8 a0 = *(const s16x8*)(arow);
            s16x8 a1 = *(const s16x8*)(arow + 32);
            wsync();                            // a-frags in regs; region reusable

            // ---- msg MFMAs (bf16, [ch][edge] layout, packed b64 writes) ----
            #pragma unroll
            for (int t2 = 0; t2 < 4; ++t2) {
                const float bvt = bv4[t2];
                f32x4 acc = {bvt, bvt, bvt, bvt};   // fold base bias into C
                acc = __builtin_amdgcn_mfma_f32_16x16x32_bf16(a0, bfr[t2][0], acc, 0, 0, 0);
                acc = __builtin_amdgcn_mfma_f32_16x16x32_bf16(a1, bfr[t2][1], acc, 0, 0, 0);
                unsigned u0 = cvt_pk_bf16(silu_f(acc[0]), silu_f(acc[1]));
                unsigned u1 = cvt_pk_bf16(silu_f(acc[2]), silu_f(acc[3]));
                *reinterpret_cast<uint2*>(msgb + (t2*16+lo16)*20 + hi*4) = (uint2){u0, u1};
            }
            wsync();                            // msg tile visible

            // ---- segmented reduce (lane = channel), b64 msg reads ----
            int rows = cnt64 - i*16; if (rows > 16) rows = 16;
            #pragma unroll
            for (int rb = 0; rb < 4; ++rb) {
                if (rb*4 < rows) {
                    uint2 mm = *reinterpret_cast<const uint2*>(msgb + lane*20 + rb*4);
                    float m0 = __uint_as_float(mm.x << 16);
                    float m1 = __uint_as_float(mm.x & 0xffff0000u);
                    float m2 = __uint_as_float(mm.y << 16);
                    float m3 = __uint_as_float(mm.y & 0xffff0000u);
                    #pragma unroll
                    for (int rr = 0; rr < 4; ++rr) {
                        int rl = rb*4 + rr;
                        if (rl < rows) {
                            int nd = dstl[i*16 + rl];   // uniform
                            if (nd != curn) {           // wave-uniform branch
                                if (curn >= 0) {
                                    int nl = curn - n0;
                                    agg_l[nl*72 + lane]     = (unsigned short)cvt_pk_bf16(s0, s0);
                                    v_l[(nl*3+0)*64 + lane] = (unsigned short)cvt_pk_bf16(sva, sva);
                                    v_l[(nl*3+1)*64 + lane] = (unsigned short)cvt_pk_bf16(svb, svb);
                                    v_l[(nl*3+2)*64 + lane] = (unsigned short)cvt_pk_bf16(svc, svc);
                                }
                                s0 = sva = svb = svc = 0.f;
                                curn = nd;
                            }
                            float4 q2 = edge4[i*16 + rl];
                            float m = rr==0 ? m0 : rr==1 ? m1 : rr==2 ? m2 : m3;
                            s0 += m;
                            sva = fmaf(q2.x, m, sva);
                            svb = fmaf(q2.y, m, svb);
                            svc = fmaf(q2.z, m, svc);
                        }
                    }
                }
            }
            wsync();                            // seg reads done before next stage
        }
        ebase = nb;
        cnt64 = eend - ebase; if (cnt64 > 64) cnt64 = 64;
    }
    if (curn >= 0) {
        int nl = curn - n0;
        agg_l[nl*72 + lane]     = (unsigned short)cvt_pk_bf16(s0, s0);
        v_l[(nl*3+0)*64 + lane] = (unsigned short)cvt_pk_bf16(sva, sva);
        v_l[(nl*3+1)*64 + lane] = (unsigned short)cvt_pk_bf16(svb, svb);
        v_l[(nl*3+2)*64 + lane] = (unsigned short)cvt_pk_bf16(svc, svc);
    }
    wsync();

    // ---- node phase: gate = silu(h + silu(agg@Wu)) * wdec; out = vm * (v . gate) ----
    s16x8 wub[4][2];
    #pragma unroll
    for (int t2 = 0; t2 < 4; ++t2)
        #pragma unroll
        for (int s = 0; s < 2; ++s)
            wub[t2][s] = *(const s16x8*)(wfrag + 4096 + ((t2*2+s)*64 + lane)*8);
    const float tb = sb ? tarr[1] : tarr[0];
    float hb4[4], wd4[4];
    #pragma unroll
    for (int t2 = 0; t2 < 4; ++t2) {
        hb4[t2] = Wsp[t2*16+lo16] + tb * Wt[t2*16+lo16];
        wd4[t2] = wdec[t2*16+lo16];
    }
    // A-tile: rows 0..3 real agg, rows 4..15 garbage (guarded below)
    s16x8 ga0 = *(const s16x8*)(agg_l + lo16*72 + hi*8);
    s16x8 ga1 = *(const s16x8*)(agg_l + lo16*72 + hi*8 + 32);
    float p[4][3] = {{0.f,0.f,0.f},{0.f,0.f,0.f},{0.f,0.f,0.f},{0.f,0.f,0.f}};
    #pragma unroll
    for (int t2 = 0; t2 < 4; ++t2) {
        f32x4 accg = {0.f, 0.f, 0.f, 0.f};
        accg = __builtin_amdgcn_mfma_f32_16x16x32_bf16(ga0, wub[t2][0], accg, 0, 0, 0);
        accg = __builtin_amdgcn_mfma_f32_16x16x32_bf16(ga1, wub[t2][1], accg, 0, 0, 0);
        #pragma unroll
        for (int r = 0; r < 4; ++r) {
            int node = hi*4 + r;
            float hn   = hb4[t2] + silu_f(accg[r]);
            float gate = silu_f(hn) * wd4[t2];
            if (node < 4) {
                #pragma unroll
                for (int c = 0; c < 3; ++c) {
                    float vv = bf16f(v_l[(node*3+c)*64 + t2*16 + lo16]);
                    p[r][c] = fmaf(gate, vv, p[r][c]);
                }
            }
        }
    }
    #pragma unroll
    for (int st = 1; st < 16; st <<= 1)
        #pragma unroll
        for (int r = 0; r < 4; ++r)
            #pragma unroll
            for (int c = 0; c < 3; ++c)
                p[r][c] += __shfl_xor(p[r][c], st, 64);

    if (lo16 < 12 && hi == 0) {
        int rr = lo16 / 3, c = lo16 - rr*3;
        float val = rr==0 ? (c==0 ? p[0][0] : c==1 ? p[0][1] : p[0][2])
                  : rr==1 ? (c==0 ? p[1][0] : c==1 ? p[1][1] : p[1][2])
                  : rr==2 ? (c==0 ? p[2][0] : c==1 ? p[2][1] : p[2][2])
                  :         (c==0 ? p[3][0] : c==1 ? p[3][1] : p[3][2]);
        out[(n0 + rr)*3 + c] = val * vm[n0 + rr];
    }
}

extern "C" void kernel_launch(void* const* d_in, const int* in_sizes, int n_in,
                              void* d_out, int out_size, void* d_ws, size_t ws_size,
                              hipStream_t stream) {
    const float* x    = (const float*)d_in[0];
    const float* t    = (const float*)d_in[1];
    const float* cell = (const float*)d_in[2];
    const float* x1   = (const float*)d_in[3];
    const float* vm   = (const float*)d_in[4];
    const float* Wsp  = (const float*)d_in[5];
    const float* Wt   = (const float*)d_in[6];
    const float* We   = (const float*)d_in[7];
    const float* Wm   = (const float*)d_in[8];
    const float* Wu   = (const float*)d_in[9];
    const float* wdec = (const float*)d_in[10];
    const int*   ei   = (const int*)d_in[11];
    const int*   tj   = (const int*)d_in[12];
    float* out = (float*)d_out;

    // ws layout (float units):
    float*  ws      = (float*)d_ws;
    float4* srec    = (float4*)ws;                   // [524288] f4
    int*    sdst    = (int*)(ws + 2097152);          // [524288]
    float*  pos     = ws + 2621440;                  // [98304]
    int*    rank    = (int*)(pos + 98304);           // [524288]
    int*    rowptr  = rank + 524288;                 // [32784 pad]
    int*    cnt     = rowptr + 32784;                // [32768]
    float*  base_ws = (float*)(cnt + 32768);         // [128]
    unsigned short* wfrag = (unsigned short*)(base_ws + 128);  // [10240]

    hipMemsetAsync(cnt, 0, 32768*sizeof(int), stream);
    k_prep_hist_base<<<2049, 256, 0, stream>>>(x, x1, vm, pos, ei, cnt, rank,
                                               Wsp, Wt, Wm, Wu, We, t, base_ws, wfrag);
    k_scan<<<8, 1024, 0, stream>>>(cnt, rowptr);
    k_sortgeo<<<2048, 256, 0, stream>>>(ei, tj, pos, cell, rowptr, rank, srec, sdst);
    k_edge_all<<<4096, 128, 0, stream>>>(srec, sdst, rowptr, wfrag, base_ws,
                                         Wsp, Wt, wdec, t, vm, out);
}

// Round 15
// 87.346 us; speedup vs baseline: 1.5032x; 1.2501x over previous
//
#include <hip/hip_runtime.h>
#include <math.h>

#define NNODE 32768     // B*T*N
#define NEDGE 524288    // NNODE * DEG
#define DD 64           // feature dim D

typedef float  f32x4 __attribute__((ext_vector_type(4)));
typedef short  s16x8 __attribute__((ext_vector_type(8)));

__device__ __forceinline__ float silu_f(float x) {
    return x * __builtin_amdgcn_rcpf(1.0f + __expf(-x));
}
__device__ __forceinline__ unsigned cvt_pk_bf16(float a, float b) {
    unsigned r;
    asm("v_cvt_pk_bf16_f32 %0, %1, %2" : "=v"(r) : "v"(a), "v"(b));
    return r;   // [15:0]=bf16(a), [31:16]=bf16(b), RNE
}
__device__ __forceinline__ unsigned short bf16r(float f) {
    unsigned u = __float_as_uint(f);
    unsigned r = (u + 0x7FFFu + ((u >> 16) & 1u)) >> 16;
    return (unsigned short)r;
}
__device__ __forceinline__ float bf16f(unsigned short u) {
    return __uint_as_float(((unsigned)u) << 16);
}
// wave-private LDS ordering: wait LDS ops, pin scheduling (no s_barrier!)
__device__ __forceinline__ void wsync() {
    asm volatile("s_waitcnt lgkmcnt(0)" ::: "memory");
    __builtin_amdgcn_sched_barrier(0);
}

// fused: pos prep (blocks 0..127) + XCD-swizzled dst histogram/rank (0..2047)
//        + wfrag (2048..2055, parallel) + base (2056)
__global__ __launch_bounds__(256) void k_prep_hist_base(
    const float* __restrict__ x, const float* __restrict__ x1,
    const float* __restrict__ vm, float* __restrict__ pos,
    const int* __restrict__ ei, int* __restrict__ cnt, int* __restrict__ rank,
    const float* __restrict__ Wsp, const float* __restrict__ Wt,
    const float* __restrict__ Wm, const float* __restrict__ Wu,
    const float* __restrict__ We, const float* __restrict__ tarr,
    float* __restrict__ base_ws, unsigned short* __restrict__ wfrag)
{
    int tid = threadIdx.x, b = blockIdx.x;
    if (b >= 2048) {
        if (b < 2056) {
            // wfrag[0:4096) = W_msg[128:192] B-frags; [4096:8192) = W_upd B-frags;
            // [8192:10240) = W_edge B-frags (K=4 padded to 32). 1280 per block.
            #pragma unroll
            for (int j = 0; j < 5; ++j) {
                int idx = (b - 2048) * 1280 + j * 256 + tid;
                unsigned short v;
                if (idx < 8192) {
                    int sel = idx >> 12, id2 = idx & 4095;
                    int jj = id2 & 7;
                    int ln = (id2 >> 3) & 63;
                    int ts = id2 >> 9;
                    int t2 = ts >> 1, s = ts & 1;
                    int k   = s*32 + (ln >> 4)*8 + jj;
                    int col = t2*16 + (ln & 15);
                    v = bf16r(sel ? Wu[k*DD + col] : Wm[(128 + k)*DD + col]);
                } else {
                    int id3 = idx - 8192;
                    int jj = id3 & 7, ln = (id3 >> 3) & 63, t2 = id3 >> 9;
                    v = (ln < 16 && jj < 4) ? bf16r(We[jj*DD + t2*16 + (ln & 15)])
                                            : (unsigned short)0;
                }
                wfrag[idx] = v;
            }
        } else if (tid < 64) {
            float t0 = tarr[0], t1 = tarr[1];
            float aA = 0.0f, aB = 0.0f;
            #pragma unroll 8
            for (int k = 0; k < DD; ++k) {
                float w = Wm[k*DD + tid] + Wm[(DD+k)*DD + tid];
                aA = fmaf(Wsp[k] + t0*Wt[k], w, aA);
                aB = fmaf(Wsp[k] + t1*Wt[k], w, aB);
            }
            base_ws[tid]      = aA;
            base_ws[DD + tid] = aB;
        }
        return;
    }
    if (b < 128) {
        int i = b*256 + tid;
        float m = vm[i];
        #pragma unroll
        for (int c = 0; c < 3; ++c)
            pos[i*3+c] = x[i*3+c]*m + x1[i*3+c]*(1.0f-m);
    }
    // XCD-swizzled: structure = b&7 -> histogram atomics hit the local L2 slice
    int e = (b & 7) * 65536 + (b >> 3) * 256 + tid;
    rank[e] = atomicAdd(&cnt[ei[NEDGE + e]], 1);
}

// per-structure exclusive scan (each structure has exactly 65536 edges)
__global__ __launch_bounds__(1024) void k_scan(
    const int* __restrict__ cnt, int* __restrict__ rowptr)
{
    __shared__ int buf[2][1024];
    const int g = blockIdx.x;          // 8 blocks
    const int tid = threadIdx.x;
    int4 L = ((const int4*)cnt)[g*1024 + tid];
    int s = L.x + L.y + L.z + L.w;
    buf[0][tid] = s;
    __syncthreads();
    int pp = 0;
    for (int off = 1; off < 1024; off <<= 1) {
        int v = buf[pp][tid];
        if (tid >= off) v += buf[pp][tid - off];
        buf[pp^1][tid] = v;
        __syncthreads();
        pp ^= 1;
    }
    int ex = (tid ? buf[pp][tid-1] : 0) + g*65536;
    int4 o;
    o.x = ex; ex += L.x;
    o.y = ex; ex += L.y;
    o.z = ex; ex += L.z;
    o.w = ex; ex += L.w;
    ((int4*)rowptr)[g*1024 + tid] = o;
    if (g == 7 && tid == 1023) rowptr[32768] = NEDGE;
}

// geometry + counting-sort scatter (XCD-swizzled): srec[slot]={ev,len}, sdst[slot]=dst
__global__ __launch_bounds__(256) void k_sortgeo(
    const int* __restrict__ ei, const int* __restrict__ tj,
    const float* __restrict__ pos, const float* __restrict__ cell,
    const int* __restrict__ rowptr, const int* __restrict__ rank,
    float4* __restrict__ srec, int* __restrict__ sdst)
{
    int b = blockIdx.x;                              // 2048 blocks
    int e = (b & 7) * 65536 + (b >> 3) * 256 + threadIdx.x;
    int g = b & 7;
    int src = ei[e];
    int dst = ei[NEDGE + e];
    const float* cl = cell + g*9;
    float c00=cl[0],c01=cl[1],c02=cl[2],c10=cl[3],c11=cl[4],c12=cl[5],c20=cl[6],c21=cl[7],c22=cl[8];
    float tj0 = (float)tj[e*3+0], tj1 = (float)tj[e*3+1], tj2 = (float)tj[e*3+2];
    float ev0 = pos[dst*3+0] - pos[src*3+0] + tj0*c00 + tj1*c10 + tj2*c20;
    float ev1 = pos[dst*3+1] - pos[src*3+1] + tj0*c01 + tj1*c11 + tj2*c21;
    float ev2 = pos[dst*3+2] - pos[src*3+2] + tj0*c02 + tj1*c12 + tj2*c22;
    float len = sqrtf(ev0*ev0 + ev1*ev1 + ev2*ev2 + 1e-12f);
    int slot = rowptr[dst] + rank[e];
    srec[slot] = (float4){ev0, ev1, ev2, len};
    sdst[slot] = dst;
}

// One wave (64-thread block) per 4-node group (8192 blocks). CSR slice,
// coalesced sorted reads + register prefetch, ea via MFMA, per-node agg/v in
// LDS (exclusive, no atomics), fused gate+readout.
// r15: msgb un-aliased from ealds + post-segred drain removed -> 2 drains per
// subtile (was 4); segmented-reduce boundaries via per-window ballot mask
// (no per-row dstl reads/compares).
__global__ __launch_bounds__(64) void k_edge_all(
    const float4* __restrict__ srec, const int* __restrict__ sdst,
    const int* __restrict__ rowptr,
    const unsigned short* __restrict__ wfrag,
    const float* __restrict__ base_ws,
    const float* __restrict__ Wsp, const float* __restrict__ Wt,
    const float* __restrict__ wdec, const float* __restrict__ tarr,
    const float* __restrict__ vm, float* __restrict__ out)
{
    const int lane = threadIdx.x;
    const int lo16 = lane & 15;
    const int hi   = lane >> 4;
    const int grp  = (blockIdx.x & 7) * 1024 + (blockIdx.x >> 3);  // XCD-local slice
    const int n0   = grp * 4;

    // LDS 8320 B (single wave, un-aliased regions):
    // @0 edge4 f4[64] | @1024 dstl i32[64] | @1280 ealds u16[16][72] (2304)
    // @3584 msgb u16[64][20] (2560) | @6144 agg_l u16[4][72] (576) | @6720 v_l u16[12][64] (1536)
    // (node-phase A-reads from agg_l overrun into v_l; rows>=4 garbage, guarded)
    __shared__ __align__(16) char my[8320];
    float4*         edge4 = (float4*)my;
    int*            dstl  = (int*)(my + 1024);
    unsigned short* ealds = (unsigned short*)(my + 1280);
    unsigned short* msgb  = (unsigned short*)(my + 3584);
    unsigned short* agg_l = (unsigned short*)(my + 6144);
    unsigned short* v_l   = (unsigned short*)(my + 6720);

    // zero agg_l (4 rows) + v_l: 576+1536 B = 528 dwords
    {
        int* zp = (int*)(my + 6144);
        #pragma unroll
        for (int j = 0; j < 9; ++j) {
            int o = j*64 + lane;
            if (o < 528) zp[o] = 0;
        }
    }

    // hot uniforms (node-phase constants loaded later)
    s16x8 bfr[4][2], wfe[4];
    #pragma unroll
    for (int t2 = 0; t2 < 4; ++t2) {
        #pragma unroll
        for (int s = 0; s < 2; ++s)
            bfr[t2][s] = *(const s16x8*)(wfrag + ((t2*2+s)*64 + lane)*8);
        wfe[t2] = *(const s16x8*)(wfrag + 8192 + (t2*64 + lane)*8);
    }
    const bool  sb  = (n0 >> 14) != 0;         // batch
    float bv4[4];
    #pragma unroll
    for (int t2 = 0; t2 < 4; ++t2)
        bv4[t2] = base_ws[(sb ? DD : 0) + t2*16 + lo16];

    const int estart = rowptr[n0];
    const int eend   = rowptr[n0 + 4];

    int   curn = -1, lastdst = -1;
    float s0 = 0.f, sva = 0.f, svb = 0.f, svc = 0.f;

    int ebase = estart;
    int cnt64 = eend - ebase; if (cnt64 > 64) cnt64 = 64;
    float4 r_rec = {0.f,0.f,0.f,0.f};
    int    r_dst = 0;
    if (ebase < eend) {
        int ii = ebase + (lane < cnt64 ? lane : cnt64 - 1);
        r_rec = srec[ii];
        r_dst = sdst[ii];
    }

    while (ebase < eend) {
        edge4[lane] = r_rec;
        dstl[lane]  = r_dst;
        wsync();                                // window visible (wave-private)

        // boundary mask (wave-uniform): bit rl set where a new dst run starts
        int prev = __shfl_up(r_dst, 1, 64);
        if (lane == 0) prev = lastdst;
        unsigned long long bmask = __ballot(r_dst != prev);
        lastdst = __shfl(r_dst, 63, 64);        // tail lanes duplicate last valid

        // prefetch next window (stays in flight under compute)
        int nb = ebase + 64;
        if (nb < eend) {
            int c2 = eend - nb; if (c2 > 64) c2 = 64;
            int jj = nb + (lane < c2 ? lane : c2 - 1);
            r_rec = srec[jj];
            r_dst = sdst[jj];
        }

        int nsub = (cnt64 + 15) >> 4;
        for (int i = 0; i < nsub; ++i) {
            // ---- ea stage via MFMA (K=4 in a 16x16x32) ----
            // (prior subtile's segred msgb reads drained by DRAIN1 below before
            //  this subtile's msg writes; ealds writes safe: prior frag reads
            //  drained by prior DRAIN2)
            float4 q = edge4[i*16 + lo16];      // 16 rows, broadcast across hi
            unsigned pa0 = cvt_pk_bf16(q.x, q.y);
            unsigned pa1 = cvt_pk_bf16(q.z, q.w);
            uint4 av = (hi == 0) ? (uint4){pa0, pa1, 0u, 0u}
                                 : (uint4){0u, 0u, 0u, 0u};
            s16x8 aea = *reinterpret_cast<s16x8*>(&av);
            #pragma unroll
            for (int t2 = 0; t2 < 4; ++t2) {
                f32x4 pre = {0.f, 0.f, 0.f, 0.f};
                pre = __builtin_amdgcn_mfma_f32_16x16x32_bf16(aea, wfe[t2], pre, 0, 0, 0);
                #pragma unroll
                for (int r = 0; r < 4; ++r)
                    ealds[(hi*4+r)*72 + t2*16 + lo16] =
                        (unsigned short)cvt_pk_bf16(silu_f(pre[r]), 0.f);
            }
            wsync();                            // DRAIN1: ea visible (+ prior segred reads done)

            const unsigned short* arow = ealds + lo16*72 + hi*8;
            s16x8 a0 = *(const s16x8*)(arow);
            s16x8 a1 = *(const s16x8*)(arow + 32);
            // (no drain: msgb is a separate region; a0/a1 data-dep waits auto)

            // ---- msg MFMAs (bf16, [ch][edge] layout, packed b64 writes) ----
            #pragma unroll
            for (int t2 = 0; t2 < 4; ++t2) {
                const float bvt = bv4[t2];
                f32x4 acc = {bvt, bvt, bvt, bvt};   // fold base bias into C
                acc = __builtin_amdgcn_mfma_f32_16x16x32_bf16(a0, bfr[t2][0], acc, 0, 0, 0);
                acc = __builtin_amdgcn_mfma_f32_16x16x32_bf16(a1, bfr[t2][1], acc, 0, 0, 0);
                unsigned u0 = cvt_pk_bf16(silu_f(acc[0]), silu_f(acc[1]));
                unsigned u1 = cvt_pk_bf16(silu_f(acc[2]), silu_f(acc[3]));
                *reinterpret_cast<uint2*>(msgb + (t2*16+lo16)*20 + hi*4) = (uint2){u0, u1};
            }
            wsync();                            // DRAIN2: msg visible

            // ---- segmented reduce (lane = channel), ballot-mask boundaries ----
            int rows = cnt64 - i*16; if (rows > 16) rows = 16;
            #pragma unroll
            for (int rb = 0; rb < 4; ++rb) {
                if (rb*4 < rows) {
                    uint2 mm = *reinterpret_cast<const uint2*>(msgb + lane*20 + rb*4);
                    float m0 = __uint_as_float(mm.x << 16);
                    float m1 = __uint_as_float(mm.x & 0xffff0000u);
                    float m2 = __uint_as_float(mm.y << 16);
                    float m3 = __uint_as_float(mm.y & 0xffff0000u);
                    #pragma unroll
                    for (int rr = 0; rr < 4; ++rr) {
                        int rl = rb*4 + rr;
                        if (rl < rows) {
                            if ((bmask >> (i*16 + rl)) & 1) {   // wave-uniform bit test
                                if (curn >= 0) {
                                    int nl = curn - n0;
                                    agg_l[nl*72 + lane]     = (unsigned short)cvt_pk_bf16(s0, s0);
                                    v_l[(nl*3+0)*64 + lane] = (unsigned short)cvt_pk_bf16(sva, sva);
                                    v_l[(nl*3+1)*64 + lane] = (unsigned short)cvt_pk_bf16(svb, svb);
                                    v_l[(nl*3+2)*64 + lane] = (unsigned short)cvt_pk_bf16(svc, svc);
                                }
                                s0 = sva = svb = svc = 0.f;
                                curn = dstl[i*16 + rl];         // rare LDS read
                            }
                            float4 q2 = edge4[i*16 + rl];
                            float m = rr==0 ? m0 : rr==1 ? m1 : rr==2 ? m2 : m3;
                            s0 += m;
                            sva = fmaf(q2.x, m, sva);
                            svb = fmaf(q2.y, m, svb);
                            svc = fmaf(q2.z, m, svc);
                        }
                    }
                }
            }
            // (no drain: next subtile's DRAIN1 covers these reads)
        }
        ebase = nb;
        cnt64 = eend - ebase; if (cnt64 > 64) cnt64 = 64;
    }
    if (curn >= 0) {
        int nl = curn - n0;
        agg_l[nl*72 + lane]     = (unsigned short)cvt_pk_bf16(s0, s0);
        v_l[(nl*3+0)*64 + lane] = (unsigned short)cvt_pk_bf16(sva, sva);
        v_l[(nl*3+1)*64 + lane] = (unsigned short)cvt_pk_bf16(svb, svb);
        v_l[(nl*3+2)*64 + lane] = (unsigned short)cvt_pk_bf16(svc, svc);
    }
    wsync();

    // ---- node phase: gate = silu(h + silu(agg@Wu)) * wdec; out = vm * (v . gate) ----
    s16x8 wub[4][2];
    #pragma unroll
    for (int t2 = 0; t2 < 4; ++t2)
        #pragma unroll
        for (int s = 0; s < 2; ++s)
            wub[t2][s] = *(const s16x8*)(wfrag + 4096 + ((t2*2+s)*64 + lane)*8);
    const float tb = sb ? tarr[1] : tarr[0];
    float hb4[4], wd4[4];
    #pragma unroll
    for (int t2 = 0; t2 < 4; ++t2) {
        hb4[t2] = Wsp[t2*16+lo16] + tb * Wt[t2*16+lo16];
        wd4[t2] = wdec[t2*16+lo16];
    }
    // A-tile: rows 0..3 real agg, rows 4..15 garbage (guarded below)
    s16x8 ga0 = *(const s16x8*)(agg_l + lo16*72 + hi*8);
    s16x8 ga1 = *(const s16x8*)(agg_l + lo16*72 + hi*8 + 32);
    float p[4][3] = {{0.f,0.f,0.f},{0.f,0.f,0.f},{0.f,0.f,0.f},{0.f,0.f,0.f}};
    #pragma unroll
    for (int t2 = 0; t2 < 4; ++t2) {
        f32x4 accg = {0.f, 0.f, 0.f, 0.f};
        accg = __builtin_amdgcn_mfma_f32_16x16x32_bf16(ga0, wub[t2][0], accg, 0, 0, 0);
        accg = __builtin_amdgcn_mfma_f32_16x16x32_bf16(ga1, wub[t2][1], accg, 0, 0, 0);
        #pragma unroll
        for (int r = 0; r < 4; ++r) {
            int node = hi*4 + r;
            float hn   = hb4[t2] + silu_f(accg[r]);
            float gate = silu_f(hn) * wd4[t2];
            if (node < 4) {
                #pragma unroll
                for (int c = 0; c < 3; ++c) {
                    float vv = bf16f(v_l[(node*3+c)*64 + t2*16 + lo16]);
                    p[r][c] = fmaf(gate, vv, p[r][c]);
                }
            }
        }
    }
    #pragma unroll
    for (int st = 1; st < 16; st <<= 1)
        #pragma unroll
        for (int r = 0; r < 4; ++r)
            #pragma unroll
            for (int c = 0; c < 3; ++c)
                p[r][c] += __shfl_xor(p[r][c], st, 64);

    if (lo16 < 12 && hi == 0) {
        int rr = lo16 / 3, c = lo16 - rr*3;
        float val = rr==0 ? (c==0 ? p[0][0] : c==1 ? p[0][1] : p[0][2])
                  : rr==1 ? (c==0 ? p[1][0] : c==1 ? p[1][1] : p[1][2])
                  : rr==2 ? (c==0 ? p[2][0] : c==1 ? p[2][1] : p[2][2])
                  :         (c==0 ? p[3][0] : c==1 ? p[3][1] : p[3][2]);
        out[(n0 + rr)*3 + c] = val * vm[n0 + rr];
    }
}

extern "C" void kernel_launch(void* const* d_in, const int* in_sizes, int n_in,
                              void* d_out, int out_size, void* d_ws, size_t ws_size,
                              hipStream_t stream) {
    const float* x    = (const float*)d_in[0];
    const float* t    = (const float*)d_in[1];
    const float* cell = (const float*)d_in[2];
    const float* x1   = (const float*)d_in[3];
    const float* vm   = (const float*)d_in[4];
    const float* Wsp  = (const float*)d_in[5];
    const float* Wt   = (const float*)d_in[6];
    const float* We   = (const float*)d_in[7];
    const float* Wm   = (const float*)d_in[8];
    const float* Wu   = (const float*)d_in[9];
    const float* wdec = (const float*)d_in[10];
    const int*   ei   = (const int*)d_in[11];
    const int*   tj   = (const int*)d_in[12];
    float* out = (float*)d_out;

    // ws layout (float units):
    float*  ws      = (float*)d_ws;
    float4* srec    = (float4*)ws;                   // [524288] f4
    int*    sdst    = (int*)(ws + 2097152);          // [524288]
    float*  pos     = ws + 2621440;                  // [98304]
    int*    rank    = (int*)(pos + 98304);           // [524288]
    int*    rowptr  = rank + 524288;                 // [32784 pad]
    int*    cnt     = rowptr + 32784;                // [32768]
    float*  base_ws = (float*)(cnt + 32768);         // [128]
    unsigned short* wfrag = (unsigned short*)(base_ws + 128);  // [10240]

    hipMemsetAsync(cnt, 0, 32768*sizeof(int), stream);
    k_prep_hist_base<<<2057, 256, 0, stream>>>(x, x1, vm, pos, ei, cnt, rank,
                                               Wsp, Wt, Wm, Wu, We, t, base_ws, wfrag);
    k_scan<<<8, 1024, 0, stream>>>(cnt, rowptr);
    k_sortgeo<<<2048, 256, 0, stream>>>(ei, tj, pos, cell, rowptr, rank, srec, sdst);
    k_edge_all<<<8192, 64, 0, stream>>>(srec, sdst, rowptr, wfrag, base_ws,
                                        Wsp, Wt, wdec, t, vm, out);
}